// Round 19
// baseline (1491.848 us; speedup 1.0000x reference)
//
#include <hip/hip_runtime.h>
#include <math.h>

#define B 4
#define C 200
#define H 128
#define W 128
#define N 16384   // H*W
#define K 256
#define ITERS 5
#define FACT 1.25f   // COMPACTNESS / S = 10 / 8
#define NT 32        // split-K n-tiles for the update GEMM (512 n each)
#define NCT 5        // c-tiles for the update GEMM (40 c each)

// workspace layout (floats)
#define OFF_A2    0
#define OFF_CS    (OFF_A2 + B*N)            // 65536
#define OFF_CSPAT (OFF_CS + B*K*C)          // 270336
#define OFF_B2    (OFF_CSPAT + B*K*2)       // 272384
#define OFF_SACC  (OFF_B2 + B*K)            // 273408
#define OFF_MACC  (OFF_SACC + B*K*C)        // 478208
#define OFF_SPACC (OFF_MACC + B*K)          // 479232
#define OFF_CST   (OFF_SPACC + B*K*2)       // 481280  transposed centers [B][C][K]
#define CST_SZ    (B*C*K)                   // 204800
#define OFF_PART  (OFF_CST + CST_SZ)        // 686080
#define PART_SZ   (B*NT*NCT*40*K)           // 6,553,600 floats (26.2 MB)
#define OFF_MPART (OFF_PART + PART_SZ)
#define MPART_SZ  (B*NT*3*K)                // 98,304 floats
#define WS_NEED   ((size_t)(OFF_MPART + MPART_SZ) * 4)

// ---------------------------------------------------------------------------
// init: centers_spectral[b,k,c] = x[0,c,seed_n(k)]; also transposed cs_t
__global__ void k_init(const float* __restrict__ x, float* __restrict__ cs,
                       float* __restrict__ cst, float* __restrict__ cspat) {
  int k = blockIdx.x, c = threadIdx.x;
  int i = k >> 4, j = k & 15;
  int sn = (4 + 8*i)*W + (4 + 8*j);
  if (c < C) {
    float v = x[(size_t)c*N + sn];
    for (int b = 0; b < B; ++b) {
      cs[((size_t)(b*K + k))*C + c] = v;
      cst[((size_t)(b*C + c))*K + k] = v;
    }
  }
  if (c == 0) {
    for (int b = 0; b < B; ++b) {
      cspat[(b*K + k)*2 + 0] = (float)(4 + 8*i);
      cspat[(b*K + k)*2 + 1] = (float)(4 + 8*j);
    }
  }
}

// a2[b,n] = sum_c x[b,c,n]^2  (iteration-invariant)
__global__ void k_a2(const float* __restrict__ x, float* __restrict__ a2) {
  int b = blockIdx.x >> 6;
  int n = ((blockIdx.x & 63) << 8) + threadIdx.x;
  const float* xp = x + (size_t)b*C*N + n;
  float s = 0.f;
  #pragma unroll 8
  for (int c = 0; c < C; ++c) { float v = xp[(size_t)c*N]; s += v*v; }
  a2[b*N + n] = s;
}

// b2[b,k] = sum_c cs[b,k,c]^2
__global__ void k_b2(const float* __restrict__ cs, float* __restrict__ b2) {
  int bk = blockIdx.x;
  const float* p = cs + (size_t)bk*C;
  float s = 0.f;
  for (int c = threadIdx.x; c < C; c += 64) { float v = p[c]; s += v*v; }
  for (int off = 32; off > 0; off >>= 1) s += __shfl_down(s, off);
  if (threadIdx.x == 0) b2[bk] = s;
}

// ---------------------------------------------------------------------------
// assignment v10 (unchanged from R16): register-tiled GEMM, 8k x 8px/thread.
__global__ __launch_bounds__(512, 2) void k_assign(
    const float* __restrict__ x, const float* __restrict__ cst,
    const float* __restrict__ cspat, const float* __restrict__ b2,
    const float* __restrict__ a2, float* __restrict__ Q) {
  __shared__ float cs_lds[40*K];    // 40960 B [c][k]
  __shared__ float xr_lds[40*128];  // 20480 B [c][p]; reused as redp/redf
  __shared__ float b2s[K], cys[K], cxs[K];  // 3072 B
  float* redp = xr_lds;             // [32][136] = 4352 floats
  float* redf = xr_lds + 4352;      // [128]

  int b   = blockIdx.x >> 7;          // 128 blocks per batch
  int n0  = (blockIdx.x & 127) << 7;  // 128 pixels per block
  int tid = threadIdx.x;
  int kgi = tid >> 4;                 // 0..31
  int k0  = kgi << 3;                 // 8 k per thread
  int p0  = (tid & 15) << 3;          // 8 px per thread

  if (tid < K) {
    b2s[tid] = b2[b*K + tid];
    cys[tid] = cspat[(b*K + tid)*2 + 0];
    cxs[tid] = cspat[(b*K + tid)*2 + 1];
  }

  float acc[64];   // [kk][pp] = acc[kk*8+pp]
  #pragma unroll
  for (int i = 0; i < 64; ++i) acc[i] = 0.f;

  const float* xb = x + (size_t)b*C*N;
  const float* ct = cst + (size_t)b*C*K;
  float4* cs4 = (float4*)cs_lds;
  float4* xr4 = (float4*)xr_lds;

  for (int t = 0; t < 5; ++t) {
    int cc0 = t * 40;
    __syncthreads();
    #pragma unroll
    for (int pass = 0; pass < 5; ++pass) {   // cs_t tile: linear copy 2560 f4
      int f = pass*512 + tid;
      cs4[f] = *(const float4*)&ct[(size_t)cc0*K + f*4];
    }
    #pragma unroll
    for (int pass = 0; pass < 3; ++pass) {   // x tile [40c][128p]: 1280 f4
      int idx = pass*512 + tid;
      if (idx < 1280) {
        int ci = idx >> 5, pq = idx & 31;
        xr4[idx] = *(const float4*)&xb[(size_t)(cc0 + ci)*N + n0 + pq*4];
      }
    }
    __syncthreads();
    #pragma unroll 2
    for (int c = 0; c < 40; ++c) {
      float4 cv0 = *(const float4*)&cs_lds[c*256 + k0];
      float4 cv1 = *(const float4*)&cs_lds[c*256 + k0 + 4];
      float4 xv0 = *(const float4*)&xr_lds[c*128 + p0];
      float4 xv1 = *(const float4*)&xr_lds[c*128 + p0 + 4];
      float cr[8] = {cv0.x, cv0.y, cv0.z, cv0.w, cv1.x, cv1.y, cv1.z, cv1.w};
      float xr[8] = {xv0.x, xv0.y, xv0.z, xv0.w, xv1.x, xv1.y, xv1.z, xv1.w};
      #pragma unroll
      for (int kk = 0; kk < 8; ++kk)
        #pragma unroll
        for (int pp = 0; pp < 8; ++pp)
          acc[kk*8 + pp] = fmaf(cr[kk], xr[pp], acc[kk*8 + pp]);
    }
  }
  __syncthreads();   // all x_lds reads done before redp overlay writes

  // ---- distances ----
  float py  = (float)(n0 >> 7);          // all 128 px share one image row
  float pxb = (float)(n0 & 127);
  float a2v[8], mn[8];
  #pragma unroll
  for (int pp = 0; pp < 8; ++pp) {
    a2v[pp] = a2[b*N + n0 + p0 + pp];
    mn[pp] = 1e30f;
  }
  #pragma unroll
  for (int kk = 0; kk < 8; ++kk) {
    int k = k0 + kk;
    float b2v = b2s[k], cy = cys[k], cx = cxs[k];
    float dy = py - cy, dyy = dy*dy;
    #pragma unroll
    for (int pp = 0; pp < 8; ++pp) {
      float dx = pxb + (float)(p0 + pp) - cx;
      float d = sqrtf(fmaxf(a2v[pp] + b2v - 2.f*acc[kk*8+pp], 1e-12f))
              + FACT*sqrtf(fmaxf(dyy + dx*dx, 1e-12f));
      acc[kk*8+pp] = d;
      mn[pp] = fminf(mn[pp], d);
    }
  }
  // ---- softmax over K: two-stage reduce across 32 kgroups ----
  #pragma unroll
  for (int pp = 0; pp < 8; ++pp) redp[kgi*136 + p0 + pp] = mn[pp];
  __syncthreads();
  if (tid < 128) {
    float m = redp[tid];
    #pragma unroll
    for (int g = 1; g < 32; ++g) m = fminf(m, redp[g*136 + tid]);
    redf[tid] = m;
  }
  __syncthreads();
  #pragma unroll
  for (int pp = 0; pp < 8; ++pp) mn[pp] = redf[p0 + pp];
  float sm[8] = {0.f,0.f,0.f,0.f,0.f,0.f,0.f,0.f};
  #pragma unroll
  for (int kk = 0; kk < 8; ++kk)
    #pragma unroll
    for (int pp = 0; pp < 8; ++pp) {
      float e = __expf(mn[pp] - acc[kk*8+pp]);
      acc[kk*8+pp] = e;
      sm[pp] += e;
    }
  __syncthreads();   // redf min-reads done before sum overwrite path
  #pragma unroll
  for (int pp = 0; pp < 8; ++pp) redp[kgi*136 + p0 + pp] = sm[pp];
  __syncthreads();
  if (tid < 128) {
    float s = redp[tid];
    #pragma unroll
    for (int g = 1; g < 32; ++g) s += redp[g*136 + tid];
    redf[tid] = 1.f / s;
  }
  __syncthreads();
  #pragma unroll
  for (int pp = 0; pp < 8; ++pp) {
    float inv = redf[p0 + pp];
    float* qp = Q + ((size_t)(b*N + n0 + p0 + pp))*K + k0;
    float4 v0 = make_float4(acc[0*8+pp]*inv, acc[1*8+pp]*inv,
                            acc[2*8+pp]*inv, acc[3*8+pp]*inv);
    float4 v1 = make_float4(acc[4*8+pp]*inv, acc[5*8+pp]*inv,
                            acc[6*8+pp]*inv, acc[7*8+pp]*inv);
    *(float4*)&qp[0] = v0;
    *(float4*)&qp[4] = v1;
  }
}

// ---------------------------------------------------------------------------
// update v8 stage 1: R16-best shape (256 thr, 64kg x 4cg, acc[40], NCT=5,
// grid 640) + FUSED mass/sy/sx: wave 0 (cg==0, wave-uniform) of ct==0 blocks
// accumulates from the qr registers the inner loop already loads. k_mass gone.
__global__ __launch_bounds__(256) void k_update3(
    const float* __restrict__ x, const float* __restrict__ Q,
    float* __restrict__ part, float* __restrict__ mpart) {
  __shared__ float q_lds[32*256];   // 32 KB [n][k]
  __shared__ float x_lds[40*34];    // 5.4 KB [c][n] pad 34
  int bid = blockIdx.x;             // B*NCT*NT = 640
  int b   = bid / (NCT*NT);
  int rem = bid - b*(NCT*NT);
  int ct  = rem >> 5;               // 0..4
  int nt  = rem & 31;               // 0..31
  int tid = threadIdx.x;
  int kg  = tid & 63;               // 64 kgroups
  int k0  = kg << 2;                // 4 k per thread
  int cg  = tid >> 6;               // 4 cgroups == wave id (wave-uniform)
  int cbase = cg * 10;              // 10 c per thread
  int c0  = ct * 40;
  bool domass = (ct == 0) && (cg == 0);   // wave-uniform predicate

  float acc[40];                    // [kk][c] = acc[kk*10 + c]
  #pragma unroll
  for (int i = 0; i < 40; ++i) acc[i] = 0.f;
  float mass[4] = {0.f,0.f,0.f,0.f};
  float msy[4]  = {0.f,0.f,0.f,0.f};
  float msx[4]  = {0.f,0.f,0.f,0.f};

  const float* xb = x + (size_t)b*C*N + (size_t)c0*N;
  const float4* Q4 = (const float4*)(Q + (size_t)b*N*K);
  float4* q4 = (float4*)q_lds;

  for (int ch = 0; ch < 16; ++ch) {
    int nb = nt*512 + ch*32;
    __syncthreads();
    #pragma unroll
    for (int pass = 0; pass < 8; ++pass) {   // Q tile: 2048 f4, linear
      int idx = pass*256 + tid;
      q4[idx] = Q4[(size_t)(nb + (idx >> 6))*64 + (idx & 63)];
    }
    #pragma unroll
    for (int pass = 0; pass < 5; ++pass) {   // x tile [40c][34n]: 1280 elems
      int idx = pass*256 + tid;
      int ci = idx >> 5, nn = idx & 31;
      x_lds[ci*34 + nn] = xb[(size_t)ci*N + nb + nn];
    }
    __syncthreads();
    float py  = (float)(nb >> 7);            // chunk stays in one image row
    float pxb = (float)(nb & 127);
    #pragma unroll 4
    for (int nn = 0; nn < 32; nn += 2) {
      float4 qv0 = *(const float4*)&q_lds[nn*256 + k0];
      float4 qv1 = *(const float4*)&q_lds[(nn+1)*256 + k0];
      float qr0[4] = {qv0.x, qv0.y, qv0.z, qv0.w};
      float qr1[4] = {qv1.x, qv1.y, qv1.z, qv1.w};
      if (domass) {                          // wave-uniform, no divergence
        float px0 = pxb + (float)nn, px1 = pxb + (float)(nn + 1);
        #pragma unroll
        for (int kk = 0; kk < 4; ++kk) {
          float qs = qr0[kk] + qr1[kk];
          mass[kk] += qs;
          msy[kk]  = fmaf(py, qs, msy[kk]);
          msx[kk]  = fmaf(px0, qr0[kk], fmaf(px1, qr1[kk], msx[kk]));
        }
      }
      #pragma unroll
      for (int c = 0; c < 10; ++c) {
        float2 xv = *(const float2*)&x_lds[(cbase + c)*34 + nn]; // broadcast
        #pragma unroll
        for (int kk = 0; kk < 4; ++kk) {
          float a = acc[kk*10 + c];
          a = fmaf(qr0[kk], xv.x, a);
          a = fmaf(qr1[kk], xv.y, a);
          acc[kk*10 + c] = a;
        }
      }
    }
  }
  // coalesced f4 partial stores (consecutive kg -> consecutive 16B)
  float* pp = part + ((size_t)((b*NT + nt)*NCT + ct) * 40) * K;
  #pragma unroll
  for (int c = 0; c < 10; ++c) {
    float4 v = make_float4(acc[0*10+c], acc[1*10+c], acc[2*10+c], acc[3*10+c]);
    *(float4*)&pp[(size_t)(cbase + c)*K + k0] = v;
  }
  if (domass) {                              // wave 0 covers k0=0..252 step 4
    float* mp = mpart + (size_t)(b*NT + nt) * 3 * K;
    *(float4*)&mp[k0]       = make_float4(mass[0], mass[1], mass[2], mass[3]);
    *(float4*)&mp[K + k0]   = make_float4(msy[0], msy[1], msy[2], msy[3]);
    *(float4*)&mp[2*K + k0] = make_float4(msx[0], msx[1], msx[2], msx[3]);
  }
}

// stage 2: reduce NT partials per output element. grid = B*200.
__global__ __launch_bounds__(256) void k_reduce(
    const float* __restrict__ part, const float* __restrict__ mpart,
    float* __restrict__ sacc, float* __restrict__ macc,
    float* __restrict__ spacc) {
  int bid = blockIdx.x;        // B * 200
  int b = bid / 200;
  int r = bid % 200;
  int ct = r / 40, cw = r % 40;
  int tid = threadIdx.x;
  float s = 0.f;
  for (int nt = 0; nt < NT; ++nt)
    s += part[(((size_t)(b*NT + nt)*NCT + ct)*40 + cw)*K + tid];
  sacc[(size_t)(b*K + tid)*C + ct*40 + cw] = s;
  if (r == 0) {
    float m = 0.f, yy = 0.f, xx = 0.f;
    for (int nt = 0; nt < NT; ++nt) {
      const float* mp = mpart + (size_t)(b*NT + nt) * 3 * K;
      m  += mp[tid];
      yy += mp[K + tid];
      xx += mp[2*K + tid];
    }
    macc[b*K + tid] = m;
    spacc[(b*K + tid)*2 + 0] = yy;
    spacc[(b*K + tid)*2 + 1] = xx;
  }
}

// ---------------------------------------------------------------------------
// fallback update (atomic version, used only if ws too small for partials)
__global__ __launch_bounds__(256, 2) void k_update(
    const float* __restrict__ x, const float* __restrict__ Q,
    float* __restrict__ sacc, float* __restrict__ macc,
    float* __restrict__ spacc) {
  __shared__ float x_lds[32*28];
  int bid = blockIdx.x;
  int b = bid >> 9;
  int rest = bid & 511;
  int ct = rest >> 6;
  int nt = rest & 63;
  int tid = threadIdx.x;
  int c0 = ct * 25;

  float acc[25];
  #pragma unroll
  for (int c = 0; c < 25; ++c) acc[c] = 0.f;
  float mass = 0.f, sy = 0.f, sx = 0.f;

  const float* xb = x + (size_t)b*C*N + (size_t)c0*N;
  const float* Qb = Q + (size_t)b*N*K;

  for (int ch = 0; ch < 8; ++ch) {
    int nb = nt*256 + ch*32;
    __syncthreads();
    #pragma unroll
    for (int pass = 0; pass < 4; ++pass) {
      int idx = pass*256 + tid;
      if (idx < 800) {
        int ci = idx >> 5, nn = idx & 31;
        x_lds[nn*28 + ci] = xb[(size_t)ci*N + nb + nn];
      }
    }
    __syncthreads();
    float py  = (float)(nb >> 7);
    float pxb = (float)(nb & 127);
    #pragma unroll
    for (int n4 = 0; n4 < 8; ++n4) {
      float qv[4];
      #pragma unroll
      for (int j = 0; j < 4; ++j)
        qv[j] = Qb[(size_t)(nb + n4*4 + j)*K + tid];
      #pragma unroll
      for (int j = 0; j < 4; ++j) {
        int nn = n4*4 + j;
        float q = qv[j];
        if (ct == 0) {
          mass += q;
          sy += q * py;
          sx += q * (pxb + (float)nn);
        }
        const float* xr = &x_lds[nn*28];
        #pragma unroll
        for (int c4 = 0; c4 < 6; ++c4) {
          float4 xv = *(const float4*)&xr[c4*4];
          acc[c4*4+0] = fmaf(q, xv.x, acc[c4*4+0]);
          acc[c4*4+1] = fmaf(q, xv.y, acc[c4*4+1]);
          acc[c4*4+2] = fmaf(q, xv.z, acc[c4*4+2]);
          acc[c4*4+3] = fmaf(q, xv.w, acc[c4*4+3]);
        }
        acc[24] = fmaf(q, xr[24], acc[24]);
      }
    }
  }
  float* sp = sacc + ((size_t)(b*K + tid))*C + c0;
  #pragma unroll
  for (int c = 0; c < 25; ++c) atomicAdd(&sp[c], acc[c]);
  if (ct == 0) {
    atomicAdd(&macc[b*K + tid], mass);
    atomicAdd(&spacc[(b*K + tid)*2 + 0], sy);
    atomicAdd(&spacc[(b*K + tid)*2 + 1], sx);
  }
}

// finalize: divide by mass; write centers (row-major + transposed) and d_out
__global__ void k_final(const float* __restrict__ sacc, const float* __restrict__ macc,
                        const float* __restrict__ spacc, float* __restrict__ cs,
                        float* __restrict__ cst, float* __restrict__ cspat,
                        float* __restrict__ outc, int last) {
  int bk = blockIdx.x;
  int b = bk >> 8, kk = bk & 255;
  int c = threadIdx.x;
  float inv = 1.f / (macc[bk] + 1e-6f);
  if (c < C) {
    float v = sacc[(size_t)bk*C + c] * inv;
    cs[(size_t)bk*C + c] = v;
    cst[((size_t)(b*C + c))*K + kk] = v;
    if (last) outc[(size_t)bk*C + c] = v;
  } else if (c == C) {
    cspat[bk*2 + 0] = spacc[bk*2 + 0] * inv;
  } else if (c == C + 1) {
    cspat[bk*2 + 1] = spacc[bk*2 + 1] * inv;
  }
}

extern "C" void kernel_launch(void* const* d_in, const int* in_sizes, int n_in,
                              void* d_out, int out_size, void* d_ws, size_t ws_size,
                              hipStream_t stream) {
  const float* x = (const float*)d_in[0];
  float* out = (float*)d_out;
  float* ws  = (float*)d_ws;
  float* a2    = ws + OFF_A2;
  float* cs    = ws + OFF_CS;
  float* cspat = ws + OFF_CSPAT;
  float* b2    = ws + OFF_B2;
  float* sacc  = ws + OFF_SACC;
  float* macc  = ws + OFF_MACC;
  float* spacc = ws + OFF_SPACC;
  float* cst   = ws + OFF_CST;
  float* part  = ws + OFF_PART;
  float* mpart = ws + OFF_MPART;
  float* outc  = out + (size_t)B*N*K;
  int split = (ws_size >= WS_NEED) ? 1 : 0;

  hipLaunchKernelGGL(k_init, dim3(K), dim3(256), 0, stream, x, cs, cst, cspat);
  hipLaunchKernelGGL(k_a2, dim3(B*64), dim3(256), 0, stream, x, a2);
  for (int it = 0; it < ITERS; ++it) {
    hipLaunchKernelGGL(k_b2, dim3(B*K), dim3(64), 0, stream, cs, b2);
    hipLaunchKernelGGL(k_assign, dim3(B*128), dim3(512), 0, stream,
                       x, cst, cspat, b2, a2, out);
    if (split) {
      hipLaunchKernelGGL(k_update3, dim3(B*NCT*NT), dim3(256), 0, stream,
                         x, out, part, mpart);
      hipLaunchKernelGGL(k_reduce, dim3(B*200), dim3(256), 0, stream,
                         part, mpart, sacc, macc, spacc);
    } else {
      hipMemsetAsync(sacc, 0, (size_t)(B*K*C + B*K + B*K*2)*sizeof(float), stream);
      hipLaunchKernelGGL(k_update, dim3(B*512), dim3(256), 0, stream,
                         x, out, sacc, macc, spacc);
    }
    hipLaunchKernelGGL(k_final, dim3(B*K), dim3(256), 0, stream,
                       sacc, macc, spacc, cs, cst, cspat, outc,
                       (it == ITERS-1) ? 1 : 0);
  }
}

// Round 20
// 1207.932 us; speedup vs baseline: 1.2350x; 1.2350x over previous
//
#include <hip/hip_runtime.h>
#include <math.h>

#define B 4
#define C 200
#define H 128
#define W 128
#define N 16384   // H*W
#define K 256
#define ITERS 5
#define FACT 1.25f   // COMPACTNESS / S = 10 / 8
#define NT 32        // split-K n-tiles for the update GEMM (512 n each)
#define NTM 128      // n-tiles for k_mass (128 n each)

// workspace layout (floats)
#define OFF_A2    0
#define OFF_CS    (OFF_A2 + B*N)            // 65536
#define OFF_CSPAT (OFF_CS + B*K*C)          // 270336
#define OFF_B2    (OFF_CSPAT + B*K*2)       // 272384
#define OFF_SACC  (OFF_B2 + B*K)            // 273408
#define OFF_MACC  (OFF_SACC + B*K*C)        // 478208
#define OFF_SPACC (OFF_MACC + B*K)          // 479232
#define OFF_CST   (OFF_SPACC + B*K*2)       // 481280  transposed centers [B][C][K]
#define CST_SZ    (B*C*K)                   // 204800
#define OFF_PART  (OFF_CST + CST_SZ)        // 686080
#define PART_SZ   (B*NT*5*40*K)             // 6,553,600 floats (26.2 MB)
#define OFF_MPART (OFF_PART + PART_SZ)
#define MPART_SZ  (B*NTM*3*K)               // 393,216 floats
#define WS_NEED   ((size_t)(OFF_MPART + MPART_SZ) * 4)

// ---------------------------------------------------------------------------
// init: centers_spectral[b,k,c] = x[0,c,seed_n(k)]; also transposed cs_t
__global__ void k_init(const float* __restrict__ x, float* __restrict__ cs,
                       float* __restrict__ cst, float* __restrict__ cspat) {
  int k = blockIdx.x, c = threadIdx.x;
  int i = k >> 4, j = k & 15;
  int sn = (4 + 8*i)*W + (4 + 8*j);
  if (c < C) {
    float v = x[(size_t)c*N + sn];
    for (int b = 0; b < B; ++b) {
      cs[((size_t)(b*K + k))*C + c] = v;
      cst[((size_t)(b*C + c))*K + k] = v;
    }
  }
  if (c == 0) {
    for (int b = 0; b < B; ++b) {
      cspat[(b*K + k)*2 + 0] = (float)(4 + 8*i);
      cspat[(b*K + k)*2 + 1] = (float)(4 + 8*j);
    }
  }
}

// a2[b,n] = sum_c x[b,c,n]^2  (iteration-invariant)
__global__ void k_a2(const float* __restrict__ x, float* __restrict__ a2) {
  int b = blockIdx.x >> 6;
  int n = ((blockIdx.x & 63) << 8) + threadIdx.x;
  const float* xp = x + (size_t)b*C*N + n;
  float s = 0.f;
  #pragma unroll 8
  for (int c = 0; c < C; ++c) { float v = xp[(size_t)c*N]; s += v*v; }
  a2[b*N + n] = s;
}

// b2[b,k] = sum_c cs[b,k,c]^2  (called ONCE pre-loop; k_final updates after)
__global__ void k_b2(const float* __restrict__ cs, float* __restrict__ b2) {
  int bk = blockIdx.x;
  const float* p = cs + (size_t)bk*C;
  float s = 0.f;
  for (int c = threadIdx.x; c < C; c += 64) { float v = p[c]; s += v*v; }
  for (int off = 32; off > 0; off >>= 1) s += __shfl_down(s, off);
  if (threadIdx.x == 0) b2[bk] = s;
}

// ---------------------------------------------------------------------------
// assignment v10 (R16-best): register-tiled GEMM, 8k x 8px/thread.
__global__ __launch_bounds__(512, 2) void k_assign(
    const float* __restrict__ x, const float* __restrict__ cst,
    const float* __restrict__ cspat, const float* __restrict__ b2,
    const float* __restrict__ a2, float* __restrict__ Q) {
  __shared__ float cs_lds[40*K];    // 40960 B [c][k]
  __shared__ float xr_lds[40*128];  // 20480 B [c][p]; reused as redp/redf
  __shared__ float b2s[K], cys[K], cxs[K];  // 3072 B
  float* redp = xr_lds;             // [32][136] = 4352 floats
  float* redf = xr_lds + 4352;      // [128]

  int b   = blockIdx.x >> 7;          // 128 blocks per batch
  int n0  = (blockIdx.x & 127) << 7;  // 128 pixels per block
  int tid = threadIdx.x;
  int kgi = tid >> 4;                 // 0..31
  int k0  = kgi << 3;                 // 8 k per thread
  int p0  = (tid & 15) << 3;          // 8 px per thread

  if (tid < K) {
    b2s[tid] = b2[b*K + tid];
    cys[tid] = cspat[(b*K + tid)*2 + 0];
    cxs[tid] = cspat[(b*K + tid)*2 + 1];
  }

  float acc[64];   // [kk][pp] = acc[kk*8+pp]
  #pragma unroll
  for (int i = 0; i < 64; ++i) acc[i] = 0.f;

  const float* xb = x + (size_t)b*C*N;
  const float* ct = cst + (size_t)b*C*K;
  float4* cs4 = (float4*)cs_lds;
  float4* xr4 = (float4*)xr_lds;

  for (int t = 0; t < 5; ++t) {
    int cc0 = t * 40;
    __syncthreads();
    #pragma unroll
    for (int pass = 0; pass < 5; ++pass) {   // cs_t tile: linear copy 2560 f4
      int f = pass*512 + tid;
      cs4[f] = *(const float4*)&ct[(size_t)cc0*K + f*4];
    }
    #pragma unroll
    for (int pass = 0; pass < 3; ++pass) {   // x tile [40c][128p]: 1280 f4
      int idx = pass*512 + tid;
      if (idx < 1280) {
        int ci = idx >> 5, pq = idx & 31;
        xr4[idx] = *(const float4*)&xb[(size_t)(cc0 + ci)*N + n0 + pq*4];
      }
    }
    __syncthreads();
    #pragma unroll 2
    for (int c = 0; c < 40; ++c) {
      float4 cv0 = *(const float4*)&cs_lds[c*256 + k0];
      float4 cv1 = *(const float4*)&cs_lds[c*256 + k0 + 4];
      float4 xv0 = *(const float4*)&xr_lds[c*128 + p0];
      float4 xv1 = *(const float4*)&xr_lds[c*128 + p0 + 4];
      float cr[8] = {cv0.x, cv0.y, cv0.z, cv0.w, cv1.x, cv1.y, cv1.z, cv1.w};
      float xr[8] = {xv0.x, xv0.y, xv0.z, xv0.w, xv1.x, xv1.y, xv1.z, xv1.w};
      #pragma unroll
      for (int kk = 0; kk < 8; ++kk)
        #pragma unroll
        for (int pp = 0; pp < 8; ++pp)
          acc[kk*8 + pp] = fmaf(cr[kk], xr[pp], acc[kk*8 + pp]);
    }
  }
  __syncthreads();   // all x_lds reads done before redp overlay writes

  // ---- distances ----
  float py  = (float)(n0 >> 7);          // all 128 px share one image row
  float pxb = (float)(n0 & 127);
  float a2v[8], mn[8];
  #pragma unroll
  for (int pp = 0; pp < 8; ++pp) {
    a2v[pp] = a2[b*N + n0 + p0 + pp];
    mn[pp] = 1e30f;
  }
  #pragma unroll
  for (int kk = 0; kk < 8; ++kk) {
    int k = k0 + kk;
    float b2v = b2s[k], cy = cys[k], cx = cxs[k];
    float dy = py - cy, dyy = dy*dy;
    #pragma unroll
    for (int pp = 0; pp < 8; ++pp) {
      float dx = pxb + (float)(p0 + pp) - cx;
      float d = sqrtf(fmaxf(a2v[pp] + b2v - 2.f*acc[kk*8+pp], 1e-12f))
              + FACT*sqrtf(fmaxf(dyy + dx*dx, 1e-12f));
      acc[kk*8+pp] = d;
      mn[pp] = fminf(mn[pp], d);
    }
  }
  // ---- softmax over K: two-stage reduce across 32 kgroups ----
  #pragma unroll
  for (int pp = 0; pp < 8; ++pp) redp[kgi*136 + p0 + pp] = mn[pp];
  __syncthreads();
  if (tid < 128) {
    float m = redp[tid];
    #pragma unroll
    for (int g = 1; g < 32; ++g) m = fminf(m, redp[g*136 + tid]);
    redf[tid] = m;
  }
  __syncthreads();
  #pragma unroll
  for (int pp = 0; pp < 8; ++pp) mn[pp] = redf[p0 + pp];
  float sm[8] = {0.f,0.f,0.f,0.f,0.f,0.f,0.f,0.f};
  #pragma unroll
  for (int kk = 0; kk < 8; ++kk)
    #pragma unroll
    for (int pp = 0; pp < 8; ++pp) {
      float e = __expf(mn[pp] - acc[kk*8+pp]);
      acc[kk*8+pp] = e;
      sm[pp] += e;
    }
  __syncthreads();   // redf min-reads done before sum overwrite path
  #pragma unroll
  for (int pp = 0; pp < 8; ++pp) redp[kgi*136 + p0 + pp] = sm[pp];
  __syncthreads();
  if (tid < 128) {
    float s = redp[tid];
    #pragma unroll
    for (int g = 1; g < 32; ++g) s += redp[g*136 + tid];
    redf[tid] = 1.f / s;
  }
  __syncthreads();
  #pragma unroll
  for (int pp = 0; pp < 8; ++pp) {
    float inv = redf[p0 + pp];
    float* qp = Q + ((size_t)(b*N + n0 + p0 + pp))*K + k0;
    float4 v0 = make_float4(acc[0*8+pp]*inv, acc[1*8+pp]*inv,
                            acc[2*8+pp]*inv, acc[3*8+pp]*inv);
    float4 v1 = make_float4(acc[4*8+pp]*inv, acc[5*8+pp]*inv,
                            acc[6*8+pp]*inv, acc[7*8+pp]*inv);
    *(float4*)&qp[0] = v0;
    *(float4*)&qp[4] = v1;
  }
}

// ---------------------------------------------------------------------------
// update v5 stage 1 (R16-best): register-tiled 4k x 10c, no atomics.
// 256 thr = 64 kgroups(4k) x 4 cgroups(10c). Block = 256k x 40c x 512n.
__global__ __launch_bounds__(256) void k_update3(
    const float* __restrict__ x, const float* __restrict__ Q,
    float* __restrict__ part) {
  __shared__ float q_lds[32*256];   // 32 KB [n][k]
  __shared__ float x_lds[40*34];    // 5.4 KB [c][n] pad 34
  int bid = blockIdx.x;             // B*5*NT = 640
  int b   = bid / 160;
  int rem = bid - b*160;
  int ct  = rem >> 5;               // 0..4
  int nt  = rem & 31;               // 0..31
  int tid = threadIdx.x;
  int kg  = tid & 63;               // 64 kgroups
  int k0  = kg << 2;                // 4 k per thread
  int cg  = tid >> 6;               // 4 cgroups
  int cbase = cg * 10;              // 10 c per thread
  int c0  = ct * 40;

  float acc[40];                    // [kk][c] = acc[kk*10 + c]
  #pragma unroll
  for (int i = 0; i < 40; ++i) acc[i] = 0.f;

  const float* xb = x + (size_t)b*C*N + (size_t)c0*N;
  const float4* Q4 = (const float4*)(Q + (size_t)b*N*K);
  float4* q4 = (float4*)q_lds;

  for (int ch = 0; ch < 16; ++ch) {
    int nb = nt*512 + ch*32;
    __syncthreads();
    #pragma unroll
    for (int pass = 0; pass < 8; ++pass) {   // Q tile: 2048 f4, linear
      int idx = pass*256 + tid;
      q4[idx] = Q4[(size_t)(nb + (idx >> 6))*64 + (idx & 63)];
    }
    #pragma unroll
    for (int pass = 0; pass < 5; ++pass) {   // x tile [40c][34n]
      int idx = pass*256 + tid;
      int ci = idx >> 5, nn = idx & 31;
      x_lds[ci*34 + nn] = xb[(size_t)ci*N + nb + nn];
    }
    __syncthreads();
    #pragma unroll 4
    for (int nn = 0; nn < 32; nn += 2) {
      float4 qv0 = *(const float4*)&q_lds[nn*256 + k0];
      float4 qv1 = *(const float4*)&q_lds[(nn+1)*256 + k0];
      float qr0[4] = {qv0.x, qv0.y, qv0.z, qv0.w};
      float qr1[4] = {qv1.x, qv1.y, qv1.z, qv1.w};
      #pragma unroll
      for (int c = 0; c < 10; ++c) {
        float2 xv = *(const float2*)&x_lds[(cbase + c)*34 + nn]; // broadcast
        #pragma unroll
        for (int kk = 0; kk < 4; ++kk) {
          float a = acc[kk*10 + c];
          a = fmaf(qr0[kk], xv.x, a);
          a = fmaf(qr1[kk], xv.y, a);
          acc[kk*10 + c] = a;
        }
      }
    }
  }
  float* pp = part + ((size_t)((b*NT + nt)*5 + ct) * 40) * K;
  #pragma unroll
  for (int c = 0; c < 10; ++c) {
    float4 v = make_float4(acc[0*10+c], acc[1*10+c], acc[2*10+c], acc[3*10+c]);
    *(float4*)&pp[(size_t)(cbase + c)*K + k0] = v;
  }
}

// mass/spatial sums: mass[k] = sum_n Q[n][k], etc. grid = B*NTM, 128 n each.
__global__ __launch_bounds__(256) void k_mass(
    const float* __restrict__ Q, float* __restrict__ mpart) {
  int bid = blockIdx.x;             // B*NTM = 512
  int b = bid >> 7, nt = bid & 127;
  int tid = threadIdx.x;
  const float* Qb = Q + (size_t)b*N*K;
  int nbase = nt * 128;
  float mass = 0.f, sy = 0.f, sx = 0.f;
  for (int nn = 0; nn < 128; nn += 8) {
    float qv[8];
    #pragma unroll
    for (int j = 0; j < 8; ++j)
      qv[j] = Qb[(size_t)(nbase + nn + j)*K + tid];
    #pragma unroll
    for (int j = 0; j < 8; ++j) {
      int n = nbase + nn + j;
      mass += qv[j];
      sy += qv[j] * (float)(n >> 7);
      sx += qv[j] * (float)(n & 127);
    }
  }
  float* mp = mpart + (size_t)(b*NTM + nt) * 3 * K;
  mp[tid]       = mass;
  mp[K + tid]   = sy;
  mp[2*K + tid] = sx;
}

// stage 2: reduce NT partials per output element. grid = B*200.
__global__ __launch_bounds__(256) void k_reduce(
    const float* __restrict__ part, const float* __restrict__ mpart,
    float* __restrict__ sacc, float* __restrict__ macc,
    float* __restrict__ spacc) {
  int bid = blockIdx.x;        // B * 200
  int b = bid / 200;
  int r = bid % 200;
  int ct = r / 40, cw = r % 40;
  int tid = threadIdx.x;
  float s = 0.f;
  for (int nt = 0; nt < NT; ++nt)
    s += part[(((size_t)(b*NT + nt)*5 + ct)*40 + cw)*K + tid];
  sacc[(size_t)(b*K + tid)*C + ct*40 + cw] = s;
  if (r == 0) {
    float m = 0.f, yy = 0.f, xx = 0.f;
    for (int nt = 0; nt < NTM; ++nt) {
      const float* mp = mpart + (size_t)(b*NTM + nt) * 3 * K;
      m  += mp[tid];
      yy += mp[K + tid];
      xx += mp[2*K + tid];
    }
    macc[b*K + tid] = m;
    spacc[(b*K + tid)*2 + 0] = yy;
    spacc[(b*K + tid)*2 + 1] = xx;
  }
}

// ---------------------------------------------------------------------------
// fallback update (atomic version, used only if ws too small for partials)
__global__ __launch_bounds__(256, 2) void k_update(
    const float* __restrict__ x, const float* __restrict__ Q,
    float* __restrict__ sacc, float* __restrict__ macc,
    float* __restrict__ spacc) {
  __shared__ float x_lds[32*28];
  int bid = blockIdx.x;
  int b = bid >> 9;
  int rest = bid & 511;
  int ct = rest >> 6;
  int nt = rest & 63;
  int tid = threadIdx.x;
  int c0 = ct * 25;

  float acc[25];
  #pragma unroll
  for (int c = 0; c < 25; ++c) acc[c] = 0.f;
  float mass = 0.f, sy = 0.f, sx = 0.f;

  const float* xb = x + (size_t)b*C*N + (size_t)c0*N;
  const float* Qb = Q + (size_t)b*N*K;

  for (int ch = 0; ch < 8; ++ch) {
    int nb = nt*256 + ch*32;
    __syncthreads();
    #pragma unroll
    for (int pass = 0; pass < 4; ++pass) {
      int idx = pass*256 + tid;
      if (idx < 800) {
        int ci = idx >> 5, nn = idx & 31;
        x_lds[nn*28 + ci] = xb[(size_t)ci*N + nb + nn];
      }
    }
    __syncthreads();
    float py  = (float)(nb >> 7);
    float pxb = (float)(nb & 127);
    #pragma unroll
    for (int n4 = 0; n4 < 8; ++n4) {
      float qv[4];
      #pragma unroll
      for (int j = 0; j < 4; ++j)
        qv[j] = Qb[(size_t)(nb + n4*4 + j)*K + tid];
      #pragma unroll
      for (int j = 0; j < 4; ++j) {
        int nn = n4*4 + j;
        float q = qv[j];
        if (ct == 0) {
          mass += q;
          sy += q * py;
          sx += q * (pxb + (float)nn);
        }
        const float* xr = &x_lds[nn*28];
        #pragma unroll
        for (int c4 = 0; c4 < 6; ++c4) {
          float4 xv = *(const float4*)&xr[c4*4];
          acc[c4*4+0] = fmaf(q, xv.x, acc[c4*4+0]);
          acc[c4*4+1] = fmaf(q, xv.y, acc[c4*4+1]);
          acc[c4*4+2] = fmaf(q, xv.z, acc[c4*4+2]);
          acc[c4*4+3] = fmaf(q, xv.w, acc[c4*4+3]);
        }
        acc[24] = fmaf(q, xr[24], acc[24]);
      }
    }
  }
  float* sp = sacc + ((size_t)(b*K + tid))*C + c0;
  #pragma unroll
  for (int c = 0; c < 25; ++c) atomicAdd(&sp[c], acc[c]);
  if (ct == 0) {
    atomicAdd(&macc[b*K + tid], mass);
    atomicAdd(&spacc[(b*K + tid)*2 + 0], sy);
    atomicAdd(&spacc[(b*K + tid)*2 + 1], sx);
  }
}

// finalize: divide by mass; write centers (row-major + transposed + d_out)
// and compute b2 for the NEXT iteration (replaces per-iter k_b2 launches).
__global__ void k_final(const float* __restrict__ sacc, const float* __restrict__ macc,
                        const float* __restrict__ spacc, float* __restrict__ cs,
                        float* __restrict__ cst, float* __restrict__ cspat,
                        float* __restrict__ b2, float* __restrict__ outc, int last) {
  __shared__ float red[256];
  int bk = blockIdx.x;
  int b = bk >> 8, kk = bk & 255;
  int c = threadIdx.x;
  float inv = 1.f / (macc[bk] + 1e-6f);
  float v = 0.f;
  if (c < C) {
    v = sacc[(size_t)bk*C + c] * inv;
    cs[(size_t)bk*C + c] = v;
    cst[((size_t)(b*C + c))*K + kk] = v;
    if (last) outc[(size_t)bk*C + c] = v;
  } else if (c == C) {
    cspat[bk*2 + 0] = spacc[bk*2 + 0] * inv;
  } else if (c == C + 1) {
    cspat[bk*2 + 1] = spacc[bk*2 + 1] * inv;
  }
  // block-reduce sum of v^2 -> b2[bk]
  red[c] = v * v;
  __syncthreads();
  for (int off = 128; off > 0; off >>= 1) {
    if (c < off) red[c] += red[c + off];
    __syncthreads();
  }
  if (c == 0) b2[bk] = red[0];
}

extern "C" void kernel_launch(void* const* d_in, const int* in_sizes, int n_in,
                              void* d_out, int out_size, void* d_ws, size_t ws_size,
                              hipStream_t stream) {
  const float* x = (const float*)d_in[0];
  float* out = (float*)d_out;
  float* ws  = (float*)d_ws;
  float* a2    = ws + OFF_A2;
  float* cs    = ws + OFF_CS;
  float* cspat = ws + OFF_CSPAT;
  float* b2    = ws + OFF_B2;
  float* sacc  = ws + OFF_SACC;
  float* macc  = ws + OFF_MACC;
  float* spacc = ws + OFF_SPACC;
  float* cst   = ws + OFF_CST;
  float* part  = ws + OFF_PART;
  float* mpart = ws + OFF_MPART;
  float* outc  = out + (size_t)B*N*K;
  int split = (ws_size >= WS_NEED) ? 1 : 0;

  hipLaunchKernelGGL(k_init, dim3(K), dim3(256), 0, stream, x, cs, cst, cspat);
  hipLaunchKernelGGL(k_a2, dim3(B*64), dim3(256), 0, stream, x, a2);
  hipLaunchKernelGGL(k_b2, dim3(B*K), dim3(64), 0, stream, cs, b2);
  for (int it = 0; it < ITERS; ++it) {
    hipLaunchKernelGGL(k_assign, dim3(B*128), dim3(512), 0, stream,
                       x, cst, cspat, b2, a2, out);
    if (split) {
      hipLaunchKernelGGL(k_update3, dim3(B*5*NT), dim3(256), 0, stream,
                         x, out, part);
      hipLaunchKernelGGL(k_mass, dim3(B*NTM), dim3(256), 0, stream,
                         out, mpart);
      hipLaunchKernelGGL(k_reduce, dim3(B*200), dim3(256), 0, stream,
                         part, mpart, sacc, macc, spacc);
    } else {
      hipMemsetAsync(sacc, 0, (size_t)(B*K*C + B*K + B*K*2)*sizeof(float), stream);
      hipLaunchKernelGGL(k_update, dim3(B*512), dim3(256), 0, stream,
                         x, out, sacc, macc, spacc);
    }
    hipLaunchKernelGGL(k_final, dim3(B*K), dim3(256), 0, stream,
                       sacc, macc, spacc, cs, cst, cspat, b2, outc,
                       (it == ITERS-1) ? 1 : 0);
  }
}

// Round 21
// 994.019 us; speedup vs baseline: 1.5008x; 1.2152x over previous
//
#include <hip/hip_runtime.h>
#include <math.h>

#define B 4
#define C 200
#define H 128
#define W 128
#define N 16384   // H*W
#define K 256
#define ITERS 5
#define FACT 1.25f   // COMPACTNESS / S = 10 / 8
#define NT 32        // split-K n-tiles for the update GEMM (512 n each)
#define NTM 128      // n-tiles for k_mass (128 n each)

typedef __attribute__((ext_vector_type(8))) __bf16 bf16x8;
typedef __attribute__((ext_vector_type(4))) float f32x4;

// workspace layout (floats)
#define OFF_A2    0
#define OFF_CS    (OFF_A2 + B*N)            // 65536
#define OFF_CSPAT (OFF_CS + B*K*C)          // 270336
#define OFF_B2    (OFF_CSPAT + B*K*2)       // 272384
#define OFF_SACC  (OFF_B2 + B*K)            // 273408
#define OFF_MACC  (OFF_SACC + B*K*C)        // 478208
#define OFF_SPACC (OFF_MACC + B*K)          // 479232
#define OFF_CST   (OFF_SPACC + B*K*2)       // 481280  transposed centers [B][C][K]
#define CST_SZ    (B*C*K)                   // 204800
#define OFF_PART  (OFF_CST + CST_SZ)        // 686080
#define PART_SZ   (B*NT*5*40*K)             // 6,553,600 floats (26.2 MB)
#define OFF_MPART (OFF_PART + PART_SZ)
#define MPART_SZ  (B*NTM*3*K)               // 393,216 floats
#define WS_NEED   ((size_t)(OFF_MPART + MPART_SZ) * 4)

// ---------------------------------------------------------------------------
// init: centers_spectral[b,k,c] = x[0,c,seed_n(k)]; also transposed cs_t
__global__ void k_init(const float* __restrict__ x, float* __restrict__ cs,
                       float* __restrict__ cst, float* __restrict__ cspat) {
  int k = blockIdx.x, c = threadIdx.x;
  int i = k >> 4, j = k & 15;
  int sn = (4 + 8*i)*W + (4 + 8*j);
  if (c < C) {
    float v = x[(size_t)c*N + sn];
    for (int b = 0; b < B; ++b) {
      cs[((size_t)(b*K + k))*C + c] = v;
      cst[((size_t)(b*C + c))*K + k] = v;
    }
  }
  if (c == 0) {
    for (int b = 0; b < B; ++b) {
      cspat[(b*K + k)*2 + 0] = (float)(4 + 8*i);
      cspat[(b*K + k)*2 + 1] = (float)(4 + 8*j);
    }
  }
}

// a2[b,n] = sum_c x[b,c,n]^2  (iteration-invariant)
__global__ void k_a2(const float* __restrict__ x, float* __restrict__ a2) {
  int b = blockIdx.x >> 6;
  int n = ((blockIdx.x & 63) << 8) + threadIdx.x;
  const float* xp = x + (size_t)b*C*N + n;
  float s = 0.f;
  #pragma unroll 8
  for (int c = 0; c < C; ++c) { float v = xp[(size_t)c*N]; s += v*v; }
  a2[b*N + n] = s;
}

// b2[b,k] = sum_c cs[b,k,c]^2  (called ONCE pre-loop; k_final updates after)
__global__ void k_b2(const float* __restrict__ cs, float* __restrict__ b2) {
  int bk = blockIdx.x;
  const float* p = cs + (size_t)bk*C;
  float s = 0.f;
  for (int c = threadIdx.x; c < C; c += 64) { float v = p[c]; s += v*v; }
  for (int off = 32; off > 0; off >>= 1) s += __shfl_down(s, off);
  if (threadIdx.x == 0) b2[bk] = s;
}

// ---------------------------------------------------------------------------
// assignment v11: bf16 MFMA GEMM. 512 thr = 8 waves; wave w owns k in
// [32w,32w+32); block = 128px x 256k; C chunked 7x32 (last zero-padded).
// A = x-tile [16px][32c], B = cs-tile [32c][16k], D = 16x16 f32.
// a2/b2 exact fp32 -> only the ab term carries bf16 rounding.
__global__ __launch_bounds__(512, 2) void k_assign(
    const float* __restrict__ x, const float* __restrict__ cs,
    const float* __restrict__ cspat, const float* __restrict__ b2,
    const float* __restrict__ a2, float* __restrict__ Q) {
  __shared__ __bf16 cs_lds[K*40];    // [k][40] (32 used) 20480 B
  __shared__ __bf16 x_lds[128*40];   // [pix][40]          10240 B
  __shared__ float b2s[K], cys[K], cxs[K];   // 3072 B
  __shared__ float a2s[128];         // 512 B
  __shared__ float redw[8*128];      // 4096 B
  __shared__ float redf[128];        // 512 B

  int b   = blockIdx.x >> 7;          // 128 blocks per batch
  int n0  = (blockIdx.x & 127) << 7;  // 128 pixels per block
  int tid = threadIdx.x;
  int lane = tid & 63;
  int lr = lane & 15;                 // 0..15
  int lg = lane >> 4;                 // 0..3
  int w  = tid >> 6;                  // wave 0..7 (uniform)

  if (tid < K) {
    b2s[tid] = b2[b*K + tid];
    cys[tid] = cspat[(b*K + tid)*2 + 0];
    cxs[tid] = cspat[(b*K + tid)*2 + 1];
  }
  if (tid < 128) a2s[tid] = a2[b*N + n0 + tid];

  f32x4 acc[16];   // [nt][j] = acc[nt*2+j]
  #pragma unroll
  for (int i = 0; i < 16; ++i) acc[i] = (f32x4){0.f, 0.f, 0.f, 0.f};

  const float* xb = x + (size_t)b*C*N;
  const float* cb = cs + (size_t)b*K*C;

  for (int t = 0; t < 7; ++t) {
    int cc0 = t * 32;
    __syncthreads();   // previous tile's readers done (covers b2s/a2s init)
    #pragma unroll
    for (int pass = 0; pass < 4; ++pass) {   // cs tile [256k][32c] -> bf16
      int f = pass*512 + tid;                // 2048 float4 groups
      int k = f >> 3, c4 = (f & 7) * 4;
      float4 v = make_float4(0.f, 0.f, 0.f, 0.f);
      if (cc0 + c4 < 200) v = *(const float4*)&cb[(size_t)k*C + cc0 + c4];
      __bf16* d = &cs_lds[k*40 + c4];
      d[0] = (__bf16)v.x; d[1] = (__bf16)v.y;
      d[2] = (__bf16)v.z; d[3] = (__bf16)v.w;
    }
    #pragma unroll
    for (int pass = 0; pass < 8; ++pass) {   // x tile [128px][32c] -> bf16
      int idx = pass*512 + tid;              // 4096 elems
      int ci = idx >> 7, p = idx & 127;
      float xv = (cc0 + ci < 200) ? xb[(size_t)(cc0 + ci)*N + n0 + p] : 0.f;
      x_lds[p*40 + ci] = (__bf16)xv;
    }
    __syncthreads();
    const __bf16* bbase = &cs_lds[(w*32 + lr)*40 + lg*8];
    bf16x8 b0 = *(const bf16x8*)bbase;
    bf16x8 b1 = *(const bf16x8*)(bbase + 16*40);
    const __bf16* abase = &x_lds[lr*40 + lg*8];
    #pragma unroll
    for (int nt = 0; nt < 8; ++nt) {
      bf16x8 av = *(const bf16x8*)(abase + nt*16*40);
      acc[nt*2+0] = __builtin_amdgcn_mfma_f32_16x16x32_bf16(av, b0, acc[nt*2+0], 0, 0, 0);
      acc[nt*2+1] = __builtin_amdgcn_mfma_f32_16x16x32_bf16(av, b1, acc[nt*2+1], 0, 0, 0);
    }
  }

  // ---- distances + per-pixel min (lane holds 32 pixels x 2 k) ----
  float py = (float)(n0 >> 7);          // all 128 px share one image row
  float mArr[32];                        // [nt*4+r]
  #pragma unroll
  for (int nt = 0; nt < 8; ++nt) {
    #pragma unroll
    for (int r = 0; r < 4; ++r) {
      int pix = nt*16 + lg*4 + r;
      float a2v = a2s[pix];
      float pxv = (float)pix;
      float dmin = 1e30f;
      #pragma unroll
      for (int j = 0; j < 2; ++j) {
        int k = w*32 + j*16 + lr;
        float ab = acc[nt*2+j][r];
        float dy = py - cys[k];
        float dx = pxv - cxs[k];
        float d = sqrtf(fmaxf(a2v + b2s[k] - 2.f*ab, 1e-12f))
                + FACT*sqrtf(fmaxf(dy*dy + dx*dx, 1e-12f));
        acc[nt*2+j][r] = d;
        dmin = fminf(dmin, d);
      }
      mArr[nt*4+r] = dmin;
    }
  }
  #pragma unroll
  for (int i = 0; i < 32; ++i) {        // reduce over the 16 lr lanes
    float m = mArr[i];
    m = fminf(m, __shfl_xor(m, 1));
    m = fminf(m, __shfl_xor(m, 2));
    m = fminf(m, __shfl_xor(m, 4));
    m = fminf(m, __shfl_xor(m, 8));
    mArr[i] = m;
  }
  if (lr == 0) {
    #pragma unroll
    for (int nt = 0; nt < 8; ++nt)
      #pragma unroll
      for (int r = 0; r < 4; ++r)
        redw[w*128 + nt*16 + lg*4 + r] = mArr[nt*4+r];
  }
  __syncthreads();
  if (tid < 128) {
    float m = redw[tid];
    #pragma unroll
    for (int g = 1; g < 8; ++g) m = fminf(m, redw[g*128 + tid]);
    redf[tid] = m;
  }
  __syncthreads();
  // ---- exp + per-pixel sum ----
  #pragma unroll
  for (int nt = 0; nt < 8; ++nt) {
    #pragma unroll
    for (int r = 0; r < 4; ++r) {
      int pix = nt*16 + lg*4 + r;
      float mnv = redf[pix];             // broadcast read, no reg array
      float s = 0.f;
      #pragma unroll
      for (int j = 0; j < 2; ++j) {
        float e = __expf(mnv - acc[nt*2+j][r]);
        acc[nt*2+j][r] = e;
        s += e;
      }
      s += __shfl_xor(s, 1);
      s += __shfl_xor(s, 2);
      s += __shfl_xor(s, 4);
      s += __shfl_xor(s, 8);
      mArr[nt*4+r] = s;
    }
  }
  if (lr == 0) {
    #pragma unroll
    for (int nt = 0; nt < 8; ++nt)
      #pragma unroll
      for (int r = 0; r < 4; ++r)
        redw[w*128 + nt*16 + lg*4 + r] = mArr[nt*4+r];
  }
  __syncthreads();
  if (tid < 128) {
    float s = redw[tid];
    #pragma unroll
    for (int g = 1; g < 8; ++g) s += redw[g*128 + tid];
    redf[tid] = 1.f / s;
  }
  __syncthreads();
  // ---- Q writes ----
  float* Qb = Q + ((size_t)(b*N + n0))*K;
  #pragma unroll
  for (int nt = 0; nt < 8; ++nt) {
    #pragma unroll
    for (int r = 0; r < 4; ++r) {
      int pix = nt*16 + lg*4 + r;
      float inv = redf[pix];
      #pragma unroll
      for (int j = 0; j < 2; ++j) {
        int k = w*32 + j*16 + lr;
        Qb[(size_t)pix*K + k] = acc[nt*2+j][r] * inv;
      }
    }
  }
}

// ---------------------------------------------------------------------------
// update v5 stage 1 (R16-best): register-tiled 4k x 10c, no atomics.
// 256 thr = 64 kgroups(4k) x 4 cgroups(10c). Block = 256k x 40c x 512n.
__global__ __launch_bounds__(256) void k_update3(
    const float* __restrict__ x, const float* __restrict__ Q,
    float* __restrict__ part) {
  __shared__ float q_lds[32*256];   // 32 KB [n][k]
  __shared__ float x_lds[40*34];    // 5.4 KB [c][n] pad 34
  int bid = blockIdx.x;             // B*5*NT = 640
  int b   = bid / 160;
  int rem = bid - b*160;
  int ct  = rem >> 5;               // 0..4
  int nt  = rem & 31;               // 0..31
  int tid = threadIdx.x;
  int kg  = tid & 63;               // 64 kgroups
  int k0  = kg << 2;                // 4 k per thread
  int cg  = tid >> 6;               // 4 cgroups
  int cbase = cg * 10;              // 10 c per thread
  int c0  = ct * 40;

  float acc[40];                    // [kk][c] = acc[kk*10 + c]
  #pragma unroll
  for (int i = 0; i < 40; ++i) acc[i] = 0.f;

  const float* xb = x + (size_t)b*C*N + (size_t)c0*N;
  const float4* Q4 = (const float4*)(Q + (size_t)b*N*K);
  float4* q4 = (float4*)q_lds;

  for (int ch = 0; ch < 16; ++ch) {
    int nb = nt*512 + ch*32;
    __syncthreads();
    #pragma unroll
    for (int pass = 0; pass < 8; ++pass) {   // Q tile: 2048 f4, linear
      int idx = pass*256 + tid;
      q4[idx] = Q4[(size_t)(nb + (idx >> 6))*64 + (idx & 63)];
    }
    #pragma unroll
    for (int pass = 0; pass < 5; ++pass) {   // x tile [40c][34n]
      int idx = pass*256 + tid;
      int ci = idx >> 5, nn = idx & 31;
      x_lds[ci*34 + nn] = xb[(size_t)ci*N + nb + nn];
    }
    __syncthreads();
    #pragma unroll 4
    for (int nn = 0; nn < 32; nn += 2) {
      float4 qv0 = *(const float4*)&q_lds[nn*256 + k0];
      float4 qv1 = *(const float4*)&q_lds[(nn+1)*256 + k0];
      float qr0[4] = {qv0.x, qv0.y, qv0.z, qv0.w};
      float qr1[4] = {qv1.x, qv1.y, qv1.z, qv1.w};
      #pragma unroll
      for (int c = 0; c < 10; ++c) {
        float2 xv = *(const float2*)&x_lds[(cbase + c)*34 + nn]; // broadcast
        #pragma unroll
        for (int kk = 0; kk < 4; ++kk) {
          float a = acc[kk*10 + c];
          a = fmaf(qr0[kk], xv.x, a);
          a = fmaf(qr1[kk], xv.y, a);
          acc[kk*10 + c] = a;
        }
      }
    }
  }
  float* pp = part + ((size_t)((b*NT + nt)*5 + ct) * 40) * K;
  #pragma unroll
  for (int c = 0; c < 10; ++c) {
    float4 v = make_float4(acc[0*10+c], acc[1*10+c], acc[2*10+c], acc[3*10+c]);
    *(float4*)&pp[(size_t)(cbase + c)*K + k0] = v;
  }
}

// mass/spatial sums: mass[k] = sum_n Q[n][k], etc. grid = B*NTM, 128 n each.
__global__ __launch_bounds__(256) void k_mass(
    const float* __restrict__ Q, float* __restrict__ mpart) {
  int bid = blockIdx.x;             // B*NTM = 512
  int b = bid >> 7, nt = bid & 127;
  int tid = threadIdx.x;
  const float* Qb = Q + (size_t)b*N*K;
  int nbase = nt * 128;
  float mass = 0.f, sy = 0.f, sx = 0.f;
  for (int nn = 0; nn < 128; nn += 8) {
    float qv[8];
    #pragma unroll
    for (int j = 0; j < 8; ++j)
      qv[j] = Qb[(size_t)(nbase + nn + j)*K + tid];
    #pragma unroll
    for (int j = 0; j < 8; ++j) {
      int n = nbase + nn + j;
      mass += qv[j];
      sy += qv[j] * (float)(n >> 7);
      sx += qv[j] * (float)(n & 127);
    }
  }
  float* mp = mpart + (size_t)(b*NTM + nt) * 3 * K;
  mp[tid]       = mass;
  mp[K + tid]   = sy;
  mp[2*K + tid] = sx;
}

// stage 2: reduce NT partials per output element. grid = B*200.
__global__ __launch_bounds__(256) void k_reduce(
    const float* __restrict__ part, const float* __restrict__ mpart,
    float* __restrict__ sacc, float* __restrict__ macc,
    float* __restrict__ spacc) {
  int bid = blockIdx.x;        // B * 200
  int b = bid / 200;
  int r = bid % 200;
  int ct = r / 40, cw = r % 40;
  int tid = threadIdx.x;
  float s = 0.f;
  for (int nt = 0; nt < NT; ++nt)
    s += part[(((size_t)(b*NT + nt)*5 + ct)*40 + cw)*K + tid];
  sacc[(size_t)(b*K + tid)*C + ct*40 + cw] = s;
  if (r == 0) {
    float m = 0.f, yy = 0.f, xx = 0.f;
    for (int nt = 0; nt < NTM; ++nt) {
      const float* mp = mpart + (size_t)(b*NTM + nt) * 3 * K;
      m  += mp[tid];
      yy += mp[K + tid];
      xx += mp[2*K + tid];
    }
    macc[b*K + tid] = m;
    spacc[(b*K + tid)*2 + 0] = yy;
    spacc[(b*K + tid)*2 + 1] = xx;
  }
}

// ---------------------------------------------------------------------------
// fallback update (atomic version, used only if ws too small for partials)
__global__ __launch_bounds__(256, 2) void k_update(
    const float* __restrict__ x, const float* __restrict__ Q,
    float* __restrict__ sacc, float* __restrict__ macc,
    float* __restrict__ spacc) {
  __shared__ float x_lds[32*28];
  int bid = blockIdx.x;
  int b = bid >> 9;
  int rest = bid & 511;
  int ct = rest >> 6;
  int nt = rest & 63;
  int tid = threadIdx.x;
  int c0 = ct * 25;

  float acc[25];
  #pragma unroll
  for (int c = 0; c < 25; ++c) acc[c] = 0.f;
  float mass = 0.f, sy = 0.f, sx = 0.f;

  const float* xb = x + (size_t)b*C*N + (size_t)c0*N;
  const float* Qb = Q + (size_t)b*N*K;

  for (int ch = 0; ch < 8; ++ch) {
    int nb = nt*256 + ch*32;
    __syncthreads();
    #pragma unroll
    for (int pass = 0; pass < 4; ++pass) {
      int idx = pass*256 + tid;
      if (idx < 800) {
        int ci = idx >> 5, nn = idx & 31;
        x_lds[nn*28 + ci] = xb[(size_t)ci*N + nb + nn];
      }
    }
    __syncthreads();
    float py  = (float)(nb >> 7);
    float pxb = (float)(nb & 127);
    #pragma unroll
    for (int n4 = 0; n4 < 8; ++n4) {
      float qv[4];
      #pragma unroll
      for (int j = 0; j < 4; ++j)
        qv[j] = Qb[(size_t)(nb + n4*4 + j)*K + tid];
      #pragma unroll
      for (int j = 0; j < 4; ++j) {
        int nn = n4*4 + j;
        float q = qv[j];
        if (ct == 0) {
          mass += q;
          sy += q * py;
          sx += q * (pxb + (float)nn);
        }
        const float* xr = &x_lds[nn*28];
        #pragma unroll
        for (int c4 = 0; c4 < 6; ++c4) {
          float4 xv = *(const float4*)&xr[c4*4];
          acc[c4*4+0] = fmaf(q, xv.x, acc[c4*4+0]);
          acc[c4*4+1] = fmaf(q, xv.y, acc[c4*4+1]);
          acc[c4*4+2] = fmaf(q, xv.z, acc[c4*4+2]);
          acc[c4*4+3] = fmaf(q, xv.w, acc[c4*4+3]);
        }
        acc[24] = fmaf(q, xr[24], acc[24]);
      }
    }
  }
  float* sp = sacc + ((size_t)(b*K + tid))*C + c0;
  #pragma unroll
  for (int c = 0; c < 25; ++c) atomicAdd(&sp[c], acc[c]);
  if (ct == 0) {
    atomicAdd(&macc[b*K + tid], mass);
    atomicAdd(&spacc[(b*K + tid)*2 + 0], sy);
    atomicAdd(&spacc[(b*K + tid)*2 + 1], sx);
  }
}

// finalize: divide by mass; write centers (row-major + transposed + d_out)
// and compute b2 for the NEXT iteration (replaces per-iter k_b2 launches).
__global__ void k_final(const float* __restrict__ sacc, const float* __restrict__ macc,
                        const float* __restrict__ spacc, float* __restrict__ cs,
                        float* __restrict__ cst, float* __restrict__ cspat,
                        float* __restrict__ b2, float* __restrict__ outc, int last) {
  __shared__ float red[256];
  int bk = blockIdx.x;
  int b = bk >> 8, kk = bk & 255;
  int c = threadIdx.x;
  float inv = 1.f / (macc[bk] + 1e-6f);
  float v = 0.f;
  if (c < C) {
    v = sacc[(size_t)bk*C + c] * inv;
    cs[(size_t)bk*C + c] = v;
    cst[((size_t)(b*C + c))*K + kk] = v;
    if (last) outc[(size_t)bk*C + c] = v;
  } else if (c == C) {
    cspat[bk*2 + 0] = spacc[bk*2 + 0] * inv;
  } else if (c == C + 1) {
    cspat[bk*2 + 1] = spacc[bk*2 + 1] * inv;
  }
  // block-reduce sum of v^2 -> b2[bk]
  red[c] = v * v;
  __syncthreads();
  for (int off = 128; off > 0; off >>= 1) {
    if (c < off) red[c] += red[c + off];
    __syncthreads();
  }
  if (c == 0) b2[bk] = red[0];
}

extern "C" void kernel_launch(void* const* d_in, const int* in_sizes, int n_in,
                              void* d_out, int out_size, void* d_ws, size_t ws_size,
                              hipStream_t stream) {
  const float* x = (const float*)d_in[0];
  float* out = (float*)d_out;
  float* ws  = (float*)d_ws;
  float* a2    = ws + OFF_A2;
  float* cs    = ws + OFF_CS;
  float* cspat = ws + OFF_CSPAT;
  float* b2    = ws + OFF_B2;
  float* sacc  = ws + OFF_SACC;
  float* macc  = ws + OFF_MACC;
  float* spacc = ws + OFF_SPACC;
  float* cst   = ws + OFF_CST;
  float* part  = ws + OFF_PART;
  float* mpart = ws + OFF_MPART;
  float* outc  = out + (size_t)B*N*K;
  int split = (ws_size >= WS_NEED) ? 1 : 0;

  hipLaunchKernelGGL(k_init, dim3(K), dim3(256), 0, stream, x, cs, cst, cspat);
  hipLaunchKernelGGL(k_a2, dim3(B*64), dim3(256), 0, stream, x, a2);
  hipLaunchKernelGGL(k_b2, dim3(B*K), dim3(64), 0, stream, cs, b2);
  for (int it = 0; it < ITERS; ++it) {
    hipLaunchKernelGGL(k_assign, dim3(B*128), dim3(512), 0, stream,
                       x, cs, cspat, b2, a2, out);
    if (split) {
      hipLaunchKernelGGL(k_update3, dim3(B*5*NT), dim3(256), 0, stream,
                         x, out, part);
      hipLaunchKernelGGL(k_mass, dim3(B*NTM), dim3(256), 0, stream,
                         out, mpart);
      hipLaunchKernelGGL(k_reduce, dim3(B*200), dim3(256), 0, stream,
                         part, mpart, sacc, macc, spacc);
    } else {
      hipMemsetAsync(sacc, 0, (size_t)(B*K*C + B*K + B*K*2)*sizeof(float), stream);
      hipLaunchKernelGGL(k_update, dim3(B*512), dim3(256), 0, stream,
                         x, out, sacc, macc, spacc);
    }
    hipLaunchKernelGGL(k_final, dim3(B*K), dim3(256), 0, stream,
                       sacc, macc, spacc, cs, cst, cspat, b2, outc,
                       (it == ITERS-1) ? 1 : 0);
  }
}

// Round 22
// 668.486 us; speedup vs baseline: 2.2317x; 1.4870x over previous
//
#include <hip/hip_runtime.h>
#include <math.h>

#define B 4
#define C 200
#define H 128
#define W 128
#define N 16384   // H*W
#define K 256
#define ITERS 5
#define FACT 1.25f   // COMPACTNESS / S = 10 / 8
#define NT 32        // split-K n-tiles for the update GEMM (512 n each)
#define NTM 128      // n-tiles for k_mass (128 n each)
#define CPAD 208     // c padded to 13*16 for MFMA update

typedef __attribute__((ext_vector_type(8))) __bf16 bf16x8;
typedef __attribute__((ext_vector_type(4))) float f32x4;

// workspace layout (floats)
#define OFF_A2    0
#define OFF_CS    (OFF_A2 + B*N)            // 65536
#define OFF_CSPAT (OFF_CS + B*K*C)          // 270336
#define OFF_B2    (OFF_CSPAT + B*K*2)       // 272384
#define OFF_SACC  (OFF_B2 + B*K)            // 273408
#define OFF_MACC  (OFF_SACC + B*K*C)        // 478208
#define OFF_SPACC (OFF_MACC + B*K)          // 479232
#define OFF_CST   (OFF_SPACC + B*K*2)       // 481280  transposed centers [B][C][K]
#define CST_SZ    (B*C*K)                   // 204800
#define OFF_PART  (OFF_CST + CST_SZ)        // 686080
#define PART_SZ   (B*NT*CPAD*K)             // 6,815,744 floats (27.3 MB)
#define OFF_MPART (OFF_PART + PART_SZ)
#define MPART_SZ  (B*NTM*3*K)               // 393,216 floats
#define WS_NEED   ((size_t)(OFF_MPART + MPART_SZ) * 4)

// ---------------------------------------------------------------------------
// init: centers_spectral[b,k,c] = x[0,c,seed_n(k)]; also transposed cs_t
__global__ void k_init(const float* __restrict__ x, float* __restrict__ cs,
                       float* __restrict__ cst, float* __restrict__ cspat) {
  int k = blockIdx.x, c = threadIdx.x;
  int i = k >> 4, j = k & 15;
  int sn = (4 + 8*i)*W + (4 + 8*j);
  if (c < C) {
    float v = x[(size_t)c*N + sn];
    for (int b = 0; b < B; ++b) {
      cs[((size_t)(b*K + k))*C + c] = v;
      cst[((size_t)(b*C + c))*K + k] = v;
    }
  }
  if (c == 0) {
    for (int b = 0; b < B; ++b) {
      cspat[(b*K + k)*2 + 0] = (float)(4 + 8*i);
      cspat[(b*K + k)*2 + 1] = (float)(4 + 8*j);
    }
  }
}

// a2[b,n] = sum_c x[b,c,n]^2  (iteration-invariant)
__global__ void k_a2(const float* __restrict__ x, float* __restrict__ a2) {
  int b = blockIdx.x >> 6;
  int n = ((blockIdx.x & 63) << 8) + threadIdx.x;
  const float* xp = x + (size_t)b*C*N + n;
  float s = 0.f;
  #pragma unroll 8
  for (int c = 0; c < C; ++c) { float v = xp[(size_t)c*N]; s += v*v; }
  a2[b*N + n] = s;
}

// b2[b,k] = sum_c cs[b,k,c]^2  (called ONCE pre-loop; k_final updates after)
__global__ void k_b2(const float* __restrict__ cs, float* __restrict__ b2) {
  int bk = blockIdx.x;
  const float* p = cs + (size_t)bk*C;
  float s = 0.f;
  for (int c = threadIdx.x; c < C; c += 64) { float v = p[c]; s += v*v; }
  for (int off = 32; off > 0; off >>= 1) s += __shfl_down(s, off);
  if (threadIdx.x == 0) b2[bk] = s;
}

// ---------------------------------------------------------------------------
// assignment v11 (unchanged from R21): bf16 MFMA GEMM.
__global__ __launch_bounds__(512, 2) void k_assign(
    const float* __restrict__ x, const float* __restrict__ cs,
    const float* __restrict__ cspat, const float* __restrict__ b2,
    const float* __restrict__ a2, float* __restrict__ Q) {
  __shared__ __bf16 cs_lds[K*40];    // [k][40] (32 used) 20480 B
  __shared__ __bf16 x_lds[128*40];   // [pix][40]          10240 B
  __shared__ float b2s[K], cys[K], cxs[K];   // 3072 B
  __shared__ float a2s[128];         // 512 B
  __shared__ float redw[8*128];      // 4096 B
  __shared__ float redf[128];        // 512 B

  int b   = blockIdx.x >> 7;          // 128 blocks per batch
  int n0  = (blockIdx.x & 127) << 7;  // 128 pixels per block
  int tid = threadIdx.x;
  int lane = tid & 63;
  int lr = lane & 15;                 // 0..15
  int lg = lane >> 4;                 // 0..3
  int w  = tid >> 6;                  // wave 0..7 (uniform)

  if (tid < K) {
    b2s[tid] = b2[b*K + tid];
    cys[tid] = cspat[(b*K + tid)*2 + 0];
    cxs[tid] = cspat[(b*K + tid)*2 + 1];
  }
  if (tid < 128) a2s[tid] = a2[b*N + n0 + tid];

  f32x4 acc[16];   // [nt][j] = acc[nt*2+j]
  #pragma unroll
  for (int i = 0; i < 16; ++i) acc[i] = (f32x4){0.f, 0.f, 0.f, 0.f};

  const float* xb = x + (size_t)b*C*N;
  const float* cb = cs + (size_t)b*K*C;

  for (int t = 0; t < 7; ++t) {
    int cc0 = t * 32;
    __syncthreads();   // previous tile's readers done (covers b2s/a2s init)
    #pragma unroll
    for (int pass = 0; pass < 4; ++pass) {   // cs tile [256k][32c] -> bf16
      int f = pass*512 + tid;                // 2048 float4 groups
      int k = f >> 3, c4 = (f & 7) * 4;
      float4 v = make_float4(0.f, 0.f, 0.f, 0.f);
      if (cc0 + c4 < 200) v = *(const float4*)&cb[(size_t)k*C + cc0 + c4];
      __bf16* d = &cs_lds[k*40 + c4];
      d[0] = (__bf16)v.x; d[1] = (__bf16)v.y;
      d[2] = (__bf16)v.z; d[3] = (__bf16)v.w;
    }
    #pragma unroll
    for (int pass = 0; pass < 8; ++pass) {   // x tile [128px][32c] -> bf16
      int idx = pass*512 + tid;              // 4096 elems
      int ci = idx >> 7, p = idx & 127;
      float xv = (cc0 + ci < 200) ? xb[(size_t)(cc0 + ci)*N + n0 + p] : 0.f;
      x_lds[p*40 + ci] = (__bf16)xv;
    }
    __syncthreads();
    const __bf16* bbase = &cs_lds[(w*32 + lr)*40 + lg*8];
    bf16x8 b0 = *(const bf16x8*)bbase;
    bf16x8 b1 = *(const bf16x8*)(bbase + 16*40);
    const __bf16* abase = &x_lds[lr*40 + lg*8];
    #pragma unroll
    for (int nt = 0; nt < 8; ++nt) {
      bf16x8 av = *(const bf16x8*)(abase + nt*16*40);
      acc[nt*2+0] = __builtin_amdgcn_mfma_f32_16x16x32_bf16(av, b0, acc[nt*2+0], 0, 0, 0);
      acc[nt*2+1] = __builtin_amdgcn_mfma_f32_16x16x32_bf16(av, b1, acc[nt*2+1], 0, 0, 0);
    }
  }

  // ---- distances + per-pixel min (lane holds 32 pixels x 2 k) ----
  float py = (float)(n0 >> 7);          // all 128 px share one image row
  float mArr[32];                        // [nt*4+r]
  #pragma unroll
  for (int nt = 0; nt < 8; ++nt) {
    #pragma unroll
    for (int r = 0; r < 4; ++r) {
      int pix = nt*16 + lg*4 + r;
      float a2v = a2s[pix];
      float pxv = (float)pix;
      float dmin = 1e30f;
      #pragma unroll
      for (int j = 0; j < 2; ++j) {
        int k = w*32 + j*16 + lr;
        float ab = acc[nt*2+j][r];
        float dy = py - cys[k];
        float dx = pxv - cxs[k];
        float d = sqrtf(fmaxf(a2v + b2s[k] - 2.f*ab, 1e-12f))
                + FACT*sqrtf(fmaxf(dy*dy + dx*dx, 1e-12f));
        acc[nt*2+j][r] = d;
        dmin = fminf(dmin, d);
      }
      mArr[nt*4+r] = dmin;
    }
  }
  #pragma unroll
  for (int i = 0; i < 32; ++i) {        // reduce over the 16 lr lanes
    float m = mArr[i];
    m = fminf(m, __shfl_xor(m, 1));
    m = fminf(m, __shfl_xor(m, 2));
    m = fminf(m, __shfl_xor(m, 4));
    m = fminf(m, __shfl_xor(m, 8));
    mArr[i] = m;
  }
  if (lr == 0) {
    #pragma unroll
    for (int nt = 0; nt < 8; ++nt)
      #pragma unroll
      for (int r = 0; r < 4; ++r)
        redw[w*128 + nt*16 + lg*4 + r] = mArr[nt*4+r];
  }
  __syncthreads();
  if (tid < 128) {
    float m = redw[tid];
    #pragma unroll
    for (int g = 1; g < 8; ++g) m = fminf(m, redw[g*128 + tid]);
    redf[tid] = m;
  }
  __syncthreads();
  // ---- exp + per-pixel sum ----
  #pragma unroll
  for (int nt = 0; nt < 8; ++nt) {
    #pragma unroll
    for (int r = 0; r < 4; ++r) {
      int pix = nt*16 + lg*4 + r;
      float mnv = redf[pix];             // broadcast read, no reg array
      float s = 0.f;
      #pragma unroll
      for (int j = 0; j < 2; ++j) {
        float e = __expf(mnv - acc[nt*2+j][r]);
        acc[nt*2+j][r] = e;
        s += e;
      }
      s += __shfl_xor(s, 1);
      s += __shfl_xor(s, 2);
      s += __shfl_xor(s, 4);
      s += __shfl_xor(s, 8);
      mArr[nt*4+r] = s;
    }
  }
  if (lr == 0) {
    #pragma unroll
    for (int nt = 0; nt < 8; ++nt)
      #pragma unroll
      for (int r = 0; r < 4; ++r)
        redw[w*128 + nt*16 + lg*4 + r] = mArr[nt*4+r];
  }
  __syncthreads();
  if (tid < 128) {
    float s = redw[tid];
    #pragma unroll
    for (int g = 1; g < 8; ++g) s += redw[g*128 + tid];
    redf[tid] = 1.f / s;
  }
  __syncthreads();
  // ---- Q writes ----
  float* Qb = Q + ((size_t)(b*N + n0))*K;
  #pragma unroll
  for (int nt = 0; nt < 8; ++nt) {
    #pragma unroll
    for (int r = 0; r < 4; ++r) {
      int pix = nt*16 + lg*4 + r;
      float inv = redf[pix];
      #pragma unroll
      for (int j = 0; j < 2; ++j) {
        int k = w*32 + j*16 + lr;
        Qb[(size_t)pix*K + k] = acc[nt*2+j][r] * inv;
      }
    }
  }
}

// ---------------------------------------------------------------------------
// update v9 (MFMA): out[k][c] = sum_n Q[n,k]*x[c,n] via 16x16x32 bf16 MFMA.
// 256 thr = 4 waves; wave w = k-quarter (4 k-tiles) x 4 c-tiles (acc 64 VGPR).
// Q transposed in-kernel: stage1 q32[n][k] fp32 linear; stage2 thread-owns-k
// packs bf16 rows qbf[k][40]. x staged bf16 [c][40]. Block = 256k x 64c x 512n.
__global__ __launch_bounds__(256) void k_update4(
    const float* __restrict__ x, const float* __restrict__ Q,
    float* __restrict__ part) {
  __shared__ float  q32[32*256];    // 32768 B [n][k]
  __shared__ __bf16 qbf[256*40];    // 20480 B [k][n-pad40]
  __shared__ __bf16 xbf[64*40];     //  5120 B [c][n-pad40]
  int bid = blockIdx.x;             // B*4*NT = 512
  int b   = bid >> 7;
  int rem = bid & 127;
  int cg  = rem >> 5;               // 0..3 (c-group of 64; cg=3 holds c 192..207)
  int nt  = rem & 31;
  int tid = threadIdx.x;
  int lane = tid & 63, lr = lane & 15, lg = lane >> 4;
  int w   = tid >> 6;               // wave 0..3 = k-quarter
  int c0  = cg * 64;

  f32x4 acc[16];                    // [t][u] = acc[t*4+u]
  #pragma unroll
  for (int i = 0; i < 16; ++i) acc[i] = (f32x4){0.f, 0.f, 0.f, 0.f};

  const float* Qb = Q + (size_t)b*N*K;
  const float* xb = x + (size_t)b*C*N;

  for (int ch = 0; ch < 16; ++ch) {
    int nb = nt*512 + ch*32;
    __syncthreads();                 // prev compute done (qbf/xbf free)
    #pragma unroll
    for (int pass = 0; pass < 8; ++pass) {   // stage1: q32 [32n][256k], linear
      int f = pass*256 + tid;
      int n = f >> 6, k4 = f & 63;
      *(float4*)&q32[n*256 + k4*4] =
          *(const float4*)&Qb[(size_t)(nb + n)*K + k4*4];
    }
    #pragma unroll
    for (int pass = 0; pass < 2; ++pass) {   // stage1b: xbf [64c][40]
      int f = pass*256 + tid;
      int c = f >> 3, n4 = f & 7;
      int cc = c0 + c;
      float4 v = make_float4(0.f, 0.f, 0.f, 0.f);
      if (cc < 200) v = *(const float4*)&xb[(size_t)cc*N + nb + n4*4];
      __bf16* d = &xbf[c*40 + n4*4];
      d[0] = (__bf16)v.x; d[1] = (__bf16)v.y;
      d[2] = (__bf16)v.z; d[3] = (__bf16)v.w;
    }
    __syncthreads();
    {                                        // stage2: transpose -> qbf[k][n]
      #pragma unroll
      for (int g = 0; g < 4; ++g) {
        bf16x8 pk;
        #pragma unroll
        for (int i = 0; i < 8; ++i)
          pk[i] = (__bf16)q32[(g*8 + i)*256 + tid];
        *(bf16x8*)&qbf[tid*40 + g*8] = pk;
      }
    }
    __syncthreads();
    // compute: A = qbf rows k (w*64 + t*16 + lr), B = xbf rows c (u*16 + lr)
    const __bf16* abase = &qbf[(w*64 + lr)*40 + lg*8];
    const __bf16* bbase = &xbf[lr*40 + lg*8];
    bf16x8 A0 = *(const bf16x8*)(abase);
    bf16x8 A1 = *(const bf16x8*)(abase + 16*40);
    bf16x8 A2 = *(const bf16x8*)(abase + 32*40);
    bf16x8 A3 = *(const bf16x8*)(abase + 48*40);
    bf16x8 B0 = *(const bf16x8*)(bbase);
    bf16x8 B1 = *(const bf16x8*)(bbase + 16*40);
    bf16x8 B2 = *(const bf16x8*)(bbase + 32*40);
    bf16x8 B3 = *(const bf16x8*)(bbase + 48*40);
    acc[0]  = __builtin_amdgcn_mfma_f32_16x16x32_bf16(A0, B0, acc[0], 0, 0, 0);
    acc[1]  = __builtin_amdgcn_mfma_f32_16x16x32_bf16(A0, B1, acc[1], 0, 0, 0);
    acc[2]  = __builtin_amdgcn_mfma_f32_16x16x32_bf16(A0, B2, acc[2], 0, 0, 0);
    acc[3]  = __builtin_amdgcn_mfma_f32_16x16x32_bf16(A0, B3, acc[3], 0, 0, 0);
    acc[4]  = __builtin_amdgcn_mfma_f32_16x16x32_bf16(A1, B0, acc[4], 0, 0, 0);
    acc[5]  = __builtin_amdgcn_mfma_f32_16x16x32_bf16(A1, B1, acc[5], 0, 0, 0);
    acc[6]  = __builtin_amdgcn_mfma_f32_16x16x32_bf16(A1, B2, acc[6], 0, 0, 0);
    acc[7]  = __builtin_amdgcn_mfma_f32_16x16x32_bf16(A1, B3, acc[7], 0, 0, 0);
    acc[8]  = __builtin_amdgcn_mfma_f32_16x16x32_bf16(A2, B0, acc[8], 0, 0, 0);
    acc[9]  = __builtin_amdgcn_mfma_f32_16x16x32_bf16(A2, B1, acc[9], 0, 0, 0);
    acc[10] = __builtin_amdgcn_mfma_f32_16x16x32_bf16(A2, B2, acc[10], 0, 0, 0);
    acc[11] = __builtin_amdgcn_mfma_f32_16x16x32_bf16(A2, B3, acc[11], 0, 0, 0);
    acc[12] = __builtin_amdgcn_mfma_f32_16x16x32_bf16(A3, B0, acc[12], 0, 0, 0);
    acc[13] = __builtin_amdgcn_mfma_f32_16x16x32_bf16(A3, B1, acc[13], 0, 0, 0);
    acc[14] = __builtin_amdgcn_mfma_f32_16x16x32_bf16(A3, B2, acc[14], 0, 0, 0);
    acc[15] = __builtin_amdgcn_mfma_f32_16x16x32_bf16(A3, B3, acc[15], 0, 0, 0);
  }

  // write partials: D row=(lg*4+r) -> k, col=lr -> c
  float* pp = part + (size_t)(b*NT + nt) * CPAD * K;
  #pragma unroll
  for (int t = 0; t < 4; ++t) {
    #pragma unroll
    for (int u = 0; u < 4; ++u) {
      int c = c0 + u*16 + lr;
      if (c < CPAD) {
        int k = w*64 + t*16 + lg*4;
        *(f32x4*)&pp[(size_t)c*K + k] = acc[t*4+u];
      }
    }
  }
}

// mass/spatial sums: mass[k] = sum_n Q[n][k], etc. grid = B*NTM, 128 n each.
__global__ __launch_bounds__(256) void k_mass(
    const float* __restrict__ Q, float* __restrict__ mpart) {
  int bid = blockIdx.x;             // B*NTM = 512
  int b = bid >> 7, nt = bid & 127;
  int tid = threadIdx.x;
  const float* Qb = Q + (size_t)b*N*K;
  int nbase = nt * 128;
  float mass = 0.f, sy = 0.f, sx = 0.f;
  for (int nn = 0; nn < 128; nn += 8) {
    float qv[8];
    #pragma unroll
    for (int j = 0; j < 8; ++j)
      qv[j] = Qb[(size_t)(nbase + nn + j)*K + tid];
    #pragma unroll
    for (int j = 0; j < 8; ++j) {
      int n = nbase + nn + j;
      mass += qv[j];
      sy += qv[j] * (float)(n >> 7);
      sx += qv[j] * (float)(n & 127);
    }
  }
  float* mp = mpart + (size_t)(b*NTM + nt) * 3 * K;
  mp[tid]       = mass;
  mp[K + tid]   = sy;
  mp[2*K + tid] = sx;
}

// stage 2: reduce NT partials per output element. grid = B*200.
__global__ __launch_bounds__(256) void k_reduce(
    const float* __restrict__ part, const float* __restrict__ mpart,
    float* __restrict__ sacc, float* __restrict__ macc,
    float* __restrict__ spacc) {
  int bid = blockIdx.x;        // B * 200
  int b = bid / 200;
  int c = bid % 200;
  int tid = threadIdx.x;
  float s = 0.f;
  for (int nt = 0; nt < NT; ++nt)
    s += part[((size_t)(b*NT + nt)*CPAD + c)*K + tid];
  sacc[(size_t)(b*K + tid)*C + c] = s;
  if (c == 0) {
    float m = 0.f, yy = 0.f, xx = 0.f;
    for (int nt = 0; nt < NTM; ++nt) {
      const float* mp = mpart + (size_t)(b*NTM + nt) * 3 * K;
      m  += mp[tid];
      yy += mp[K + tid];
      xx += mp[2*K + tid];
    }
    macc[b*K + tid] = m;
    spacc[(b*K + tid)*2 + 0] = yy;
    spacc[(b*K + tid)*2 + 1] = xx;
  }
}

// ---------------------------------------------------------------------------
// fallback update (atomic version, used only if ws too small for partials)
__global__ __launch_bounds__(256, 2) void k_update(
    const float* __restrict__ x, const float* __restrict__ Q,
    float* __restrict__ sacc, float* __restrict__ macc,
    float* __restrict__ spacc) {
  __shared__ float x_lds[32*28];
  int bid = blockIdx.x;
  int b = bid >> 9;
  int rest = bid & 511;
  int ct = rest >> 6;
  int nt = rest & 63;
  int tid = threadIdx.x;
  int c0 = ct * 25;

  float acc[25];
  #pragma unroll
  for (int c = 0; c < 25; ++c) acc[c] = 0.f;
  float mass = 0.f, sy = 0.f, sx = 0.f;

  const float* xb = x + (size_t)b*C*N + (size_t)c0*N;
  const float* Qb = Q + (size_t)b*N*K;

  for (int ch = 0; ch < 8; ++ch) {
    int nb = nt*256 + ch*32;
    __syncthreads();
    #pragma unroll
    for (int pass = 0; pass < 4; ++pass) {
      int idx = pass*256 + tid;
      if (idx < 800) {
        int ci = idx >> 5, nn = idx & 31;
        x_lds[nn*28 + ci] = xb[(size_t)ci*N + nb + nn];
      }
    }
    __syncthreads();
    float py  = (float)(nb >> 7);
    float pxb = (float)(nb & 127);
    #pragma unroll
    for (int n4 = 0; n4 < 8; ++n4) {
      float qv[4];
      #pragma unroll
      for (int j = 0; j < 4; ++j)
        qv[j] = Qb[(size_t)(nb + n4*4 + j)*K + tid];
      #pragma unroll
      for (int j = 0; j < 4; ++j) {
        int nn = n4*4 + j;
        float q = qv[j];
        if (ct == 0) {
          mass += q;
          sy += q * py;
          sx += q * (pxb + (float)nn);
        }
        const float* xr = &x_lds[nn*28];
        #pragma unroll
        for (int c4 = 0; c4 < 6; ++c4) {
          float4 xv = *(const float4*)&xr[c4*4];
          acc[c4*4+0] = fmaf(q, xv.x, acc[c4*4+0]);
          acc[c4*4+1] = fmaf(q, xv.y, acc[c4*4+1]);
          acc[c4*4+2] = fmaf(q, xv.z, acc[c4*4+2]);
          acc[c4*4+3] = fmaf(q, xv.w, acc[c4*4+3]);
        }
        acc[24] = fmaf(q, xr[24], acc[24]);
      }
    }
  }
  float* sp = sacc + ((size_t)(b*K + tid))*C + c0;
  #pragma unroll
  for (int c = 0; c < 25; ++c) atomicAdd(&sp[c], acc[c]);
  if (ct == 0) {
    atomicAdd(&macc[b*K + tid], mass);
    atomicAdd(&spacc[(b*K + tid)*2 + 0], sy);
    atomicAdd(&spacc[(b*K + tid)*2 + 1], sx);
  }
}

// finalize: divide by mass; write centers (row-major + transposed + d_out)
// and compute b2 for the NEXT iteration (replaces per-iter k_b2 launches).
__global__ void k_final(const float* __restrict__ sacc, const float* __restrict__ macc,
                        const float* __restrict__ spacc, float* __restrict__ cs,
                        float* __restrict__ cst, float* __restrict__ cspat,
                        float* __restrict__ b2, float* __restrict__ outc, int last) {
  __shared__ float red[256];
  int bk = blockIdx.x;
  int b = bk >> 8, kk = bk & 255;
  int c = threadIdx.x;
  float inv = 1.f / (macc[bk] + 1e-6f);
  float v = 0.f;
  if (c < C) {
    v = sacc[(size_t)bk*C + c] * inv;
    cs[(size_t)bk*C + c] = v;
    cst[((size_t)(b*C + c))*K + kk] = v;
    if (last) outc[(size_t)bk*C + c] = v;
  } else if (c == C) {
    cspat[bk*2 + 0] = spacc[bk*2 + 0] * inv;
  } else if (c == C + 1) {
    cspat[bk*2 + 1] = spacc[bk*2 + 1] * inv;
  }
  // block-reduce sum of v^2 -> b2[bk]
  red[c] = v * v;
  __syncthreads();
  for (int off = 128; off > 0; off >>= 1) {
    if (c < off) red[c] += red[c + off];
    __syncthreads();
  }
  if (c == 0) b2[bk] = red[0];
}

extern "C" void kernel_launch(void* const* d_in, const int* in_sizes, int n_in,
                              void* d_out, int out_size, void* d_ws, size_t ws_size,
                              hipStream_t stream) {
  const float* x = (const float*)d_in[0];
  float* out = (float*)d_out;
  float* ws  = (float*)d_ws;
  float* a2    = ws + OFF_A2;
  float* cs    = ws + OFF_CS;
  float* cspat = ws + OFF_CSPAT;
  float* b2    = ws + OFF_B2;
  float* sacc  = ws + OFF_SACC;
  float* macc  = ws + OFF_MACC;
  float* spacc = ws + OFF_SPACC;
  float* cst   = ws + OFF_CST;
  float* part  = ws + OFF_PART;
  float* mpart = ws + OFF_MPART;
  float* outc  = out + (size_t)B*N*K;
  int split = (ws_size >= WS_NEED) ? 1 : 0;

  hipLaunchKernelGGL(k_init, dim3(K), dim3(256), 0, stream, x, cs, cst, cspat);
  hipLaunchKernelGGL(k_a2, dim3(B*64), dim3(256), 0, stream, x, a2);
  hipLaunchKernelGGL(k_b2, dim3(B*K), dim3(64), 0, stream, cs, b2);
  for (int it = 0; it < ITERS; ++it) {
    hipLaunchKernelGGL(k_assign, dim3(B*128), dim3(512), 0, stream,
                       x, cs, cspat, b2, a2, out);
    if (split) {
      hipLaunchKernelGGL(k_update4, dim3(B*4*NT), dim3(256), 0, stream,
                         x, out, part);
      hipLaunchKernelGGL(k_mass, dim3(B*NTM), dim3(256), 0, stream,
                         out, mpart);
      hipLaunchKernelGGL(k_reduce, dim3(B*200), dim3(256), 0, stream,
                         part, mpart, sacc, macc, spacc);
    } else {
      hipMemsetAsync(sacc, 0, (size_t)(B*K*C + B*K + B*K*2)*sizeof(float), stream);
      hipLaunchKernelGGL(k_update, dim3(B*512), dim3(256), 0, stream,
                         x, out, sacc, macc, spacc);
    }
    hipLaunchKernelGGL(k_final, dim3(B*K), dim3(256), 0, stream,
                       sacc, macc, spacc, cs, cst, cspat, b2, outc,
                       (it == ITERS-1) ? 1 : 0);
  }
}